// Round 6
// baseline (7421.853 us; speedup 1.0000x reference)
//
#include <hip/hip_runtime.h>
#include <hip/hip_bf16.h>
#include <hip/hip_fp16.h>
#include <stdint.h>

#define BB 32
#define TT 2048
#define HH 512
#define MM (BB*TT)   // 65536 rows

typedef __attribute__((ext_vector_type(8))) short bf16x8;
typedef __attribute__((ext_vector_type(4))) float f32x4;
typedef __attribute__((ext_vector_type(2))) float f32x2;
typedef __attribute__((ext_vector_type(4))) unsigned short us4;
typedef __attribute__((ext_vector_type(8))) unsigned short us8;
typedef unsigned long long u64;

__device__ __forceinline__ unsigned short f2bf(float f) {
  __hip_bfloat16 h = __float2bfloat16(f);
  return *reinterpret_cast<unsigned short*>(&h);
}
__device__ __forceinline__ float bf2f(unsigned short u) {
  return __uint_as_float(((unsigned int)u) << 16);
}

// fast sigmoid / tanh (v_exp + v_rcp; |err| ~1e-6, fine vs 0.02 budget)
__device__ __forceinline__ float fast_sigmoid(float x) {
  float e = __expf(-x);
  return __builtin_amdgcn_rcpf(1.f + e);
}
__device__ __forceinline__ float fast_tanh(float x) {
  float xc = fminf(fmaxf(x, -15.f), 15.f);
  float e2 = __expf(2.f * xc);
  return (e2 - 1.f) * __builtin_amdgcn_rcpf(e2 + 1.f);
}

// ---------------------------------------------------------------------------
// Weight convert + transpose: W[k][n] fp32 -> WT[n][k] bf16 (and hi/lo for wc_i)
// ---------------------------------------------------------------------------
__global__ void wconv_kernel(const float* __restrict__ wu, const float* __restrict__ wr,
                             const float* __restrict__ wc,
                             unsigned short* __restrict__ wuT, unsigned short* __restrict__ wrT,
                             unsigned short* __restrict__ wcTh, unsigned short* __restrict__ wcTl) {
  int idx = blockIdx.x * 256 + threadIdx.x;      // 0..262143
  int n = idx >> 9, k = idx & 511;
  int src = k * HH + n;
  wuT[idx] = f2bf(wu[src]);
  wrT[idx] = f2bf(wr[src]);
  float v = wc[src];
  unsigned short hi = f2bf(v);
  wcTh[idx] = hi;
  wcTl[idx] = f2bf(v - bf2f(hi));
}

// ---------------------------------------------------------------------------
// Projection GEMM.  A = x (M x 512 fp32, converted to bf16 tiles on the fly),
// B*T stored transposed [N][K] bf16.  BM=128 BN=64 BK=64, 256 thr / 4 waves.
// MODE 0: out = pack(f16(A@B0 + bias0), f16(A@B1 + bias1)) as u32 -> d_out
// MODE 1: out = f16(Ah@B0h + Ah@B0l + Al@B0h + bias0)             -> ws (c_x)
// ---------------------------------------------------------------------------
template<int MODE>
__global__ __launch_bounds__(256) void proj_gemm(
    const float* __restrict__ X,
    const unsigned short* __restrict__ B0T,
    const unsigned short* __restrict__ B1T,
    const float* __restrict__ bias0,
    const float* __restrict__ bias1,
    void* __restrict__ outp) {
  __shared__ __attribute__((aligned(16))) unsigned short Ah[128][72];
  __shared__ __attribute__((aligned(16))) unsigned short Al[128][72];
  __shared__ __attribute__((aligned(16))) unsigned short Bs0[64][72];
  __shared__ __attribute__((aligned(16))) unsigned short Bs1[64][72];
  const int tid = threadIdx.x;
  const int w = tid >> 6, l = tid & 63;
  const int lr = l & 15, lk = l >> 4;
  const int rowBase = blockIdx.x * 128;
  const int colBase = blockIdx.y * 64;

  f32x4 acc0[2][4], acc1[2][4];
  const f32x4 zero = {0.f, 0.f, 0.f, 0.f};
  #pragma unroll
  for (int m = 0; m < 2; ++m)
    #pragma unroll
    for (int n = 0; n < 4; ++n) { acc0[m][n] = zero; acc1[m][n] = zero; }

  for (int kt = 0; kt < 8; ++kt) {
    // stage A (fp32 -> bf16, hi/lo for MODE 1)
    #pragma unroll
    for (int i = 0; i < 8; ++i) {
      int idx = tid + 256 * i;
      int r = idx >> 4, c4 = idx & 15;
      float4 v = *reinterpret_cast<const float4*>(
          X + (size_t)(rowBase + r) * HH + kt * 64 + c4 * 4);
      us4 hv;
      hv.x = f2bf(v.x); hv.y = f2bf(v.y); hv.z = f2bf(v.z); hv.w = f2bf(v.w);
      *reinterpret_cast<us4*>(&Ah[r][c4 * 4]) = hv;
      if (MODE == 1) {
        us4 lv;
        lv.x = f2bf(v.x - bf2f(hv.x)); lv.y = f2bf(v.y - bf2f(hv.y));
        lv.z = f2bf(v.z - bf2f(hv.z)); lv.w = f2bf(v.w - bf2f(hv.w));
        *reinterpret_cast<us4*>(&Al[r][c4 * 4]) = lv;
      }
    }
    // stage B (already bf16, [n][k] layout)
    #pragma unroll
    for (int i = 0; i < 2; ++i) {
      int idx = tid + 256 * i;
      int n = idx >> 3, k8 = idx & 7;
      const size_t go = (size_t)(colBase + n) * HH + kt * 64 + k8 * 8;
      *reinterpret_cast<us8*>(&Bs0[n][k8 * 8]) = *reinterpret_cast<const us8*>(B0T + go);
      *reinterpret_cast<us8*>(&Bs1[n][k8 * 8]) = *reinterpret_cast<const us8*>(B1T + go);
    }
    __syncthreads();
    #pragma unroll
    for (int ks = 0; ks < 2; ++ks) {
      const int k0 = ks * 32 + lk * 8;
      bf16x8 a[2], b0[4], b1[4];
      #pragma unroll
      for (int m = 0; m < 2; ++m)
        a[m] = *reinterpret_cast<const bf16x8*>(&Ah[32 * w + 16 * m + lr][k0]);
      #pragma unroll
      for (int n = 0; n < 4; ++n) {
        b0[n] = *reinterpret_cast<const bf16x8*>(&Bs0[16 * n + lr][k0]);
        b1[n] = *reinterpret_cast<const bf16x8*>(&Bs1[16 * n + lr][k0]);
      }
      if (MODE == 1) {
        bf16x8 al[2];
        #pragma unroll
        for (int m = 0; m < 2; ++m)
          al[m] = *reinterpret_cast<const bf16x8*>(&Al[32 * w + 16 * m + lr][k0]);
        #pragma unroll
        for (int m = 0; m < 2; ++m)
          #pragma unroll
          for (int n = 0; n < 4; ++n) {
            acc0[m][n] = __builtin_amdgcn_mfma_f32_16x16x32_bf16(a[m],  b0[n], acc0[m][n], 0, 0, 0);
            acc0[m][n] = __builtin_amdgcn_mfma_f32_16x16x32_bf16(a[m],  b1[n], acc0[m][n], 0, 0, 0);
            acc0[m][n] = __builtin_amdgcn_mfma_f32_16x16x32_bf16(al[m], b0[n], acc0[m][n], 0, 0, 0);
          }
      } else {
        #pragma unroll
        for (int m = 0; m < 2; ++m)
          #pragma unroll
          for (int n = 0; n < 4; ++n) {
            acc0[m][n] = __builtin_amdgcn_mfma_f32_16x16x32_bf16(a[m], b0[n], acc0[m][n], 0, 0, 0);
            acc1[m][n] = __builtin_amdgcn_mfma_f32_16x16x32_bf16(a[m], b1[n], acc1[m][n], 0, 0, 0);
          }
      }
    }
    __syncthreads();
  }
  // epilogue (C/D: col = lane&15, row = (lane>>4)*4 + q)
  #pragma unroll
  for (int m = 0; m < 2; ++m) {
    #pragma unroll
    for (int n = 0; n < 4; ++n) {
      const int col = colBase + 16 * n + lr;
      const float bv0 = bias0[col];
      const float bv1 = (MODE == 0) ? bias1[col] : 0.f;
      #pragma unroll
      for (int q = 0; q < 4; ++q) {
        const int row = rowBase + 32 * w + 16 * m + lk * 4 + q;
        const size_t o = (size_t)row * HH + col;
        if (MODE == 0) {
          float v0 = acc0[m][n][q] + bv0;
          float v1 = acc1[m][n][q] + bv1;
          unsigned int pk = (unsigned int)__half_as_ushort(__float2half(v0)) |
                            ((unsigned int)__half_as_ushort(__float2half(v1)) << 16);
          reinterpret_cast<unsigned int*>(outp)[o] = pk;
        } else {
          reinterpret_cast<__half*>(outp)[o] = __float2half(acc0[m][n][q] + bv0);
        }
      }
    }
  }
}

// ---------------------------------------------------------------------------
// Persistent scan, BARRIER-FREE consumer-side reduce.
// 256 WGs x 512 thr = 2048 independent waves (b, g, w):
//   b = batch, g = publish-column group, w = k-slice / h-column group.
// Wave holds W*[k in 64w..64w+64)[j in 64g..64g+64) as f32x2 k-pairs.
//
// Iteration t (t = 0 .. TT+1):
//   1. t>=1: poll pbuf[t%3][s=0..8)[b][64w+l]: 8 tagged 8B words
//      {u16 tag | f16 au | f16 ar | f16 ac}; wait until all tags >= t.
//   2. diag wave (g==w), t>=2: out[b][t-2][64w+l] = h_{t-2}  (LAGGED write;
//      the tag chain orders it after every proj(t-2) read -- see below).
//   3. t<TT: h_t[64w+l] = GRU(h_{t-1}, sum of 8 partials, proj(t) regs);
//      issue proj(t+1) loads (in flight a full iteration).
//   4. t<=TT: matvec via readlane broadcast of h_t (t<TT-1, else zeros),
//      pack {tag=t+1, f16 partials}, ONE atomic 8B store to
//      pbuf[(t+1)%3][w][b][64g+l].   No barriers, no LDS, no fences.
//
// 3-buffer rotation safety: overwrite of buf[t%3] happens at iter t+3;
//   writer@t+3 <= (poll) pubs of (b,w,s)@t+2 <= pubs of (b,s,s')@t+1 -- which
//   covers EVERY reader of buf[t%3]@t+1 (their publish follows their read by
//   data dependence). 2 buffers provably insufficient (chain 1 step short).
// Lagged out-write safety: h_t overwrites packed proj(t) in d_out; writer@t+2
//   <= pubs@t+1 <= pubs@t whose VALUES data-depend on proj(t) loads by all 64
//   waves of batch b => every proj(t) read completed. Iterations TT, TT+1
//   publish dummy zero partials purely to extend this chain for the last two
//   out-writes.
// ---------------------------------------------------------------------------
__global__ __launch_bounds__(512, 2) void scan_kernel(
    const float* __restrict__ wu_h, const float* __restrict__ wr_h,
    const float* __restrict__ wc_h,
    float* __restrict__ out, const __half* __restrict__ cx,
    u64* __restrict__ pbuf) {           // [3][8][BB][HH] of {tag,au,ar,ac}
  const int blk = blockIdx.x;
  const int b = (blk & 7) + ((blk >> 6) << 3);   // 8 WGs of a batch share blk%8
  const int g = (blk >> 3) & 7;
  const int tid = threadIdx.x;
  const int w = tid >> 6, l = tid & 63;
  const int jg = g * 64 + l;   // column this lane publishes partials for
  const int jw = w * 64 + l;   // column this lane computes h for

  // weights: W[k][jg], k in [64w, 64w+64) as k-pair float2
  f32x2 wu2[32], wr2[32], wc2[32];
  #pragma unroll
  for (int i = 0; i < 32; ++i) {
    const size_t o0 = (size_t)(w * 64 + 2 * i) * HH + jg;
    wu2[i] = f32x2{wu_h[o0], wu_h[o0 + HH]};
    wr2[i] = f32x2{wr_h[o0], wr_h[o0 + HH]};
    wc2[i] = f32x2{wc_h[o0], wc_h[o0 + HH]};
  }

  unsigned int* outu = reinterpret_cast<unsigned int*>(out);
  const unsigned short* cxu = reinterpret_cast<const unsigned short*>(cx);
  const size_t bo = (size_t)b * TT * HH;

  unsigned int urx_c = outu[bo + jw];   // proj(0): packed {f16 u_x, f16 r_x}
  unsigned short cx_c = cxu[bo + jw];   // proj(0): f16 c_x

  float hm1 = 0.f, hm2 = 0.f;           // h_{t-1}, h_{t-2} for column jw
  const bool diag = (g == w);
  const size_t ps = (size_t)BB * HH;    // one [BB][HH] plane
  u64* const ppoll = pbuf + (size_t)b * HH + jw;
  u64* const ppub  = pbuf + (size_t)b * HH + jg;

  for (int t = 0; t <= TT + 1; ++t) {
    float su = 0.f, sr = 0.f, sc = 0.f;
    if (t >= 1) {
      const int bi = (t % 3) * 8;
      u64 v[8];
      for (;;) {
        int ok = 1;
        #pragma unroll
        for (int s = 0; s < 8; ++s)
          v[s] = __hip_atomic_load(ppoll + (size_t)(bi + s) * ps,
                                   __ATOMIC_RELAXED, __HIP_MEMORY_SCOPE_AGENT);
        #pragma unroll
        for (int s = 0; s < 8; ++s)
          ok &= (int)(((unsigned int)v[s] & 0xffffu) >= (unsigned int)t);
        if (__all(ok)) break;
      }
      if (t < TT) {
        #pragma unroll
        for (int s = 0; s < 8; ++s) {
          const unsigned int d0 = (unsigned int)v[s];
          const unsigned int d1 = (unsigned int)(v[s] >> 32);
          su += __half2float(__ushort_as_half((unsigned short)(d0 >> 16)));
          sr += __half2float(__ushort_as_half((unsigned short)(d1 & 0xffffu)));
          sc += __half2float(__ushort_as_half((unsigned short)(d1 >> 16)));
        }
      }
    }
    // lagged output write (ordered after all proj(t-2) reads via tag chain)
    if (diag && t >= 2)
      out[bo + (size_t)(t - 2) * HH + jw] = hm2;

    float hcur = hm1;
    if (t < TT) {
      const float ux = __half2float(__ushort_as_half((unsigned short)(urx_c & 0xffffu)));
      const float rx = __half2float(__ushort_as_half((unsigned short)(urx_c >> 16)));
      const float cxf = __half2float(__ushort_as_half(cx_c));
      const float uu = fast_sigmoid(su + ux);
      const float rr = fast_sigmoid(sr + rx);
      const float cc = fast_tanh(cxf + rr * sc);
      hcur = hm1 + uu * (cc - hm1);
      // issue proj(t+1) loads now; consumed next iteration (full iter in flight)
      if (t + 1 < TT) {
        urx_c = outu[bo + (size_t)(t + 1) * HH + jw];
        cx_c  = cxu[bo + (size_t)(t + 1) * HH + jw];
      }
    }
    hm2 = hm1; hm1 = hcur;

    if (t <= TT) {
      float au = 0.f, ar = 0.f, ac = 0.f;
      if (t < TT - 1) {
        const unsigned int hbits = __float_as_uint(hcur);
        f32x2 au2 = {0.f, 0.f}, ar2 = {0.f, 0.f}, ac2 = {0.f, 0.f};
        #pragma unroll
        for (int i = 0; i < 32; ++i) {
          f32x2 hp;
          hp.x = __uint_as_float(__builtin_amdgcn_readlane(hbits, 2 * i));
          hp.y = __uint_as_float(__builtin_amdgcn_readlane(hbits, 2 * i + 1));
          au2 = __builtin_elementwise_fma(hp, wu2[i], au2);
          ar2 = __builtin_elementwise_fma(hp, wr2[i], ar2);
          ac2 = __builtin_elementwise_fma(hp, wc2[i], ac2);
        }
        au = au2.x + au2.y; ar = ar2.x + ar2.y; ac = ac2.x + ac2.y;
      }
      const unsigned int d0 = (unsigned int)(t + 1) |
          ((unsigned int)__half_as_ushort(__float2half(au)) << 16);
      const unsigned int d1 = (unsigned int)__half_as_ushort(__float2half(ar)) |
          ((unsigned int)__half_as_ushort(__float2half(ac)) << 16);
      const u64 pv = ((u64)d1 << 32) | (u64)d0;
      __hip_atomic_store(ppub + (size_t)(((t + 1) % 3) * 8 + w) * ps, pv,
                         __ATOMIC_RELAXED, __HIP_MEMORY_SCOPE_AGENT);
    }
  }
}

// ---------------------------------------------------------------------------
extern "C" void kernel_launch(void* const* d_in, const int* in_sizes, int n_in,
                              void* d_out, int out_size, void* d_ws, size_t ws_size,
                              hipStream_t stream) {
  const float* x    = (const float*)d_in[0];
  const float* wu_i = (const float*)d_in[1];
  const float* wu_h = (const float*)d_in[2];
  const float* bu   = (const float*)d_in[3];
  const float* wr_i = (const float*)d_in[4];
  const float* wr_h = (const float*)d_in[5];
  const float* br   = (const float*)d_in[6];
  const float* wc_i = (const float*)d_in[7];
  const float* wc_h = (const float*)d_in[8];
  const float* bc   = (const float*)d_in[9];
  float* out = (float*)d_out;

  // ws layout (~69 MiB total)
  char* ws = (char*)d_ws;
  __half* cx = (__half*)ws;                                  // 64 MiB c_x f16
  unsigned short* wuT  = (unsigned short*)(ws + (size_t)MM * HH * 2);
  unsigned short* wrT  = wuT + HH * HH;
  unsigned short* wcTh = wrT + HH * HH;
  unsigned short* wcTl = wcTh + HH * HH;
  u64* pbuf = (u64*)(wcTl + HH * HH);                        // [3][8][BB][HH] u64 = 3 MiB

  hipMemsetAsync(pbuf, 0, (size_t)3 * 8 * BB * HH * sizeof(u64), stream);
  wconv_kernel<<<1024, 256, 0, stream>>>(wu_i, wr_i, wc_i, wuT, wrT, wcTh, wcTl);
  proj_gemm<0><<<dim3(MM / 128, 8), 256, 0, stream>>>(x, wuT, wrT, bu, br, (void*)out);
  proj_gemm<1><<<dim3(MM / 128, 8), 256, 0, stream>>>(x, wcTh, wcTl, bc, bc, (void*)cx);

  void* args[] = { (void*)&wu_h, (void*)&wr_h, (void*)&wc_h, (void*)&out,
                   (void*)&cx, (void*)&pbuf };
  hipLaunchCooperativeKernel((void*)scan_kernel, dim3(256), dim3(512), args, 0, stream);
}

// Round 7
// 4124.801 us; speedup vs baseline: 1.7993x; 1.7993x over previous
//
#include <hip/hip_runtime.h>
#include <hip/hip_bf16.h>
#include <hip/hip_fp16.h>
#include <stdint.h>

#define BB 32
#define TT 2048
#define HH 512
#define MM (BB*TT)   // 65536 rows

typedef __attribute__((ext_vector_type(8))) short bf16x8;
typedef __attribute__((ext_vector_type(4))) float f32x4;
typedef __attribute__((ext_vector_type(2))) float f32x2;
typedef __attribute__((ext_vector_type(4))) unsigned short us4;
typedef __attribute__((ext_vector_type(8))) unsigned short us8;
typedef unsigned long long u64;

__device__ __forceinline__ unsigned short f2bf(float f) {
  __hip_bfloat16 h = __float2bfloat16(f);
  return *reinterpret_cast<unsigned short*>(&h);
}
__device__ __forceinline__ float bf2f(unsigned short u) {
  return __uint_as_float(((unsigned int)u) << 16);
}

// lgkm-only workgroup barrier: does NOT drain vmcnt
__device__ __forceinline__ void wg_barrier_lgkm() {
  asm volatile("s_waitcnt lgkmcnt(0)\n\ts_barrier" ::: "memory");
}

// XCD-local fast handshake ops: sc0 = bypass L1, served by the local XCD L2
// (write-through). Same-XCD producer/consumer meet at L2 (~250cy RT) instead
// of the LLC (~600cy). Cross-XCD these can be stale -> tags are monotone so
// stale is never a false positive; the agent-scope word is the fallback.
__device__ __forceinline__ u64 load_fast(const u64* p) {
  u64 r;
  asm volatile("global_load_dwordx2 %0, %1, off sc0\n\ts_waitcnt vmcnt(0)"
               : "=&v"(r) : "v"((u64)(uintptr_t)p) : "memory");
  return r;
}
__device__ __forceinline__ void store_fast(u64* p, u64 v) {
  asm volatile("global_store_dwordx2 %0, %1, off sc0"
               :: "v"((u64)(uintptr_t)p), "v"(v) : "memory");
}

// fast sigmoid / tanh (v_exp + v_rcp; |err| ~1e-6)
__device__ __forceinline__ float fast_sigmoid(float x) {
  float e = __expf(-x);
  return __builtin_amdgcn_rcpf(1.f + e);
}
__device__ __forceinline__ float fast_tanh(float x) {
  float xc = fminf(fmaxf(x, -15.f), 15.f);
  float e2 = __expf(2.f * xc);
  return (e2 - 1.f) * __builtin_amdgcn_rcpf(e2 + 1.f);
}

// ---------------------------------------------------------------------------
// Weight convert + transpose: W[k][n] fp32 -> WT[n][k] bf16 (and hi/lo for wc_i)
// ---------------------------------------------------------------------------
__global__ void wconv_kernel(const float* __restrict__ wu, const float* __restrict__ wr,
                             const float* __restrict__ wc,
                             unsigned short* __restrict__ wuT, unsigned short* __restrict__ wrT,
                             unsigned short* __restrict__ wcTh, unsigned short* __restrict__ wcTl) {
  int idx = blockIdx.x * 256 + threadIdx.x;      // 0..262143
  int n = idx >> 9, k = idx & 511;
  int src = k * HH + n;
  wuT[idx] = f2bf(wu[src]);
  wrT[idx] = f2bf(wr[src]);
  float v = wc[src];
  unsigned short hi = f2bf(v);
  wcTh[idx] = hi;
  wcTl[idx] = f2bf(v - bf2f(hi));
}

// ---------------------------------------------------------------------------
// Projection GEMM (unchanged from R5).
// ---------------------------------------------------------------------------
template<int MODE>
__global__ __launch_bounds__(256) void proj_gemm(
    const float* __restrict__ X,
    const unsigned short* __restrict__ B0T,
    const unsigned short* __restrict__ B1T,
    const float* __restrict__ bias0,
    const float* __restrict__ bias1,
    void* __restrict__ outp) {
  __shared__ __attribute__((aligned(16))) unsigned short Ah[128][72];
  __shared__ __attribute__((aligned(16))) unsigned short Al[128][72];
  __shared__ __attribute__((aligned(16))) unsigned short Bs0[64][72];
  __shared__ __attribute__((aligned(16))) unsigned short Bs1[64][72];
  const int tid = threadIdx.x;
  const int w = tid >> 6, l = tid & 63;
  const int lr = l & 15, lk = l >> 4;
  const int rowBase = blockIdx.x * 128;
  const int colBase = blockIdx.y * 64;

  f32x4 acc0[2][4], acc1[2][4];
  const f32x4 zero = {0.f, 0.f, 0.f, 0.f};
  #pragma unroll
  for (int m = 0; m < 2; ++m)
    #pragma unroll
    for (int n = 0; n < 4; ++n) { acc0[m][n] = zero; acc1[m][n] = zero; }

  for (int kt = 0; kt < 8; ++kt) {
    #pragma unroll
    for (int i = 0; i < 8; ++i) {
      int idx = tid + 256 * i;
      int r = idx >> 4, c4 = idx & 15;
      float4 v = *reinterpret_cast<const float4*>(
          X + (size_t)(rowBase + r) * HH + kt * 64 + c4 * 4);
      us4 hv;
      hv.x = f2bf(v.x); hv.y = f2bf(v.y); hv.z = f2bf(v.z); hv.w = f2bf(v.w);
      *reinterpret_cast<us4*>(&Ah[r][c4 * 4]) = hv;
      if (MODE == 1) {
        us4 lv;
        lv.x = f2bf(v.x - bf2f(hv.x)); lv.y = f2bf(v.y - bf2f(hv.y));
        lv.z = f2bf(v.z - bf2f(hv.z)); lv.w = f2bf(v.w - bf2f(hv.w));
        *reinterpret_cast<us4*>(&Al[r][c4 * 4]) = lv;
      }
    }
    #pragma unroll
    for (int i = 0; i < 2; ++i) {
      int idx = tid + 256 * i;
      int n = idx >> 3, k8 = idx & 7;
      const size_t go = (size_t)(colBase + n) * HH + kt * 64 + k8 * 8;
      *reinterpret_cast<us8*>(&Bs0[n][k8 * 8]) = *reinterpret_cast<const us8*>(B0T + go);
      *reinterpret_cast<us8*>(&Bs1[n][k8 * 8]) = *reinterpret_cast<const us8*>(B1T + go);
    }
    __syncthreads();
    #pragma unroll
    for (int ks = 0; ks < 2; ++ks) {
      const int k0 = ks * 32 + lk * 8;
      bf16x8 a[2], b0[4], b1[4];
      #pragma unroll
      for (int m = 0; m < 2; ++m)
        a[m] = *reinterpret_cast<const bf16x8*>(&Ah[32 * w + 16 * m + lr][k0]);
      #pragma unroll
      for (int n = 0; n < 4; ++n) {
        b0[n] = *reinterpret_cast<const bf16x8*>(&Bs0[16 * n + lr][k0]);
        b1[n] = *reinterpret_cast<const bf16x8*>(&Bs1[16 * n + lr][k0]);
      }
      if (MODE == 1) {
        bf16x8 al[2];
        #pragma unroll
        for (int m = 0; m < 2; ++m)
          al[m] = *reinterpret_cast<const bf16x8*>(&Al[32 * w + 16 * m + lr][k0]);
        #pragma unroll
        for (int m = 0; m < 2; ++m)
          #pragma unroll
          for (int n = 0; n < 4; ++n) {
            acc0[m][n] = __builtin_amdgcn_mfma_f32_16x16x32_bf16(a[m],  b0[n], acc0[m][n], 0, 0, 0);
            acc0[m][n] = __builtin_amdgcn_mfma_f32_16x16x32_bf16(a[m],  b1[n], acc0[m][n], 0, 0, 0);
            acc0[m][n] = __builtin_amdgcn_mfma_f32_16x16x32_bf16(al[m], b0[n], acc0[m][n], 0, 0, 0);
          }
      } else {
        #pragma unroll
        for (int m = 0; m < 2; ++m)
          #pragma unroll
          for (int n = 0; n < 4; ++n) {
            acc0[m][n] = __builtin_amdgcn_mfma_f32_16x16x32_bf16(a[m], b0[n], acc0[m][n], 0, 0, 0);
            acc1[m][n] = __builtin_amdgcn_mfma_f32_16x16x32_bf16(a[m], b1[n], acc1[m][n], 0, 0, 0);
          }
      }
    }
    __syncthreads();
  }
  #pragma unroll
  for (int m = 0; m < 2; ++m) {
    #pragma unroll
    for (int n = 0; n < 4; ++n) {
      const int col = colBase + 16 * n + lr;
      const float bv0 = bias0[col];
      const float bv1 = (MODE == 0) ? bias1[col] : 0.f;
      #pragma unroll
      for (int q = 0; q < 4; ++q) {
        const int row = rowBase + 32 * w + 16 * m + lk * 4 + q;
        const size_t o = (size_t)row * HH + col;
        if (MODE == 0) {
          float v0 = acc0[m][n][q] + bv0;
          float v1 = acc1[m][n][q] + bv1;
          unsigned int pk = (unsigned int)__half_as_ushort(__float2half(v0)) |
                            ((unsigned int)__half_as_ushort(__float2half(v1)) << 16);
          reinterpret_cast<unsigned int*>(outp)[o] = pk;
        } else {
          reinterpret_cast<__half*>(outp)[o] = __float2half(acc0[m][n][q] + bv0);
        }
      }
    }
  }
}

// ---------------------------------------------------------------------------
// Persistent scan (R5 structure + XCD-local fast handshake).
// 256 WGs x 512 thr. WG (b,g) owns h columns [64g,64g+64); all 8 WGs of a
// batch share blk%8 (heuristically one XCD). Wave w holds W*_h[64w..64w+64)[j]
// as f32x2 k-pairs in registers.
//
// Publish: wave0 packs {tag=t+1, h_bits} in one 8B word and stores it TWICE:
//   fast word (sc0, local-L2 write-through) then slow word (agent scope, LLC).
// Poll: tight loop on the fast word; every 4th spin also check the agent word
//   with per-lane combine. Tags are monotone -> stale fast lines can never
//   false-positive; agent word bounds detection if XCD placement fails.
// Out-write: diag wave (w==g) writes out[t-1] from its polled h (lag-1); the
//   tag chain orders it after the only proj(t-1) reader (same-WG wave0).
// Reduction: parts[2][8][3][64] double-buffered, ONE lgkm barrier per step.
// ---------------------------------------------------------------------------
__global__ __launch_bounds__(512, 2) void scan_kernel(
    const float* __restrict__ wu_h, const float* __restrict__ wr_h,
    const float* __restrict__ wc_h,
    float* __restrict__ out, const __half* __restrict__ cx,
    u64* __restrict__ hfast, u64* __restrict__ hslow) {
  const int blk = blockIdx.x;
  const int b = (blk & 7) + ((blk >> 6) << 3);
  const int g = (blk >> 3) & 7;
  const int tid = threadIdx.x;
  const int w = tid >> 6, l = tid & 63;
  const int j = g * 64 + l;

  // weights as k-pair float2
  f32x2 wu2[32], wr2[32], wc2[32];
  #pragma unroll
  for (int i = 0; i < 32; ++i) {
    const size_t o0 = (size_t)(w * 64 + 2 * i) * HH + j;
    wu2[i] = f32x2{wu_h[o0], wu_h[o0 + HH]};
    wr2[i] = f32x2{wr_h[o0], wr_h[o0 + HH]};
    wc2[i] = f32x2{wc_h[o0], wc_h[o0 + HH]};
  }

  __shared__ float parts[2][8][3][64];

  float hprev = 0.f;
  unsigned int urx_c = 0;
  unsigned short cx_c = 0;
  unsigned int* outu = reinterpret_cast<unsigned int*>(out);
  const unsigned short* cxu = reinterpret_cast<const unsigned short*>(cx);
  const size_t bo = (size_t)b * TT * HH;
  if (w == 0) {
    urx_c = outu[bo + j];
    cx_c = cxu[bo + j];
  }
  u64* const fpoll = hfast + (size_t)b * HH + w * 64 + l;
  u64* const spoll = hslow + (size_t)b * HH + w * 64 + l;
  u64* const fpub  = hfast + (size_t)b * HH + j;
  u64* const spub  = hslow + (size_t)b * HH + j;
  const bool diag = (w == g);

  for (int t = 0; t <= TT; ++t) {
    float hval = 0.f;
    if (t > 0) {
      const size_t off = (size_t)(t & 1) * (BB * HH);
      u64 v = 0;
      int spin = 0;
      for (;;) {
        u64 fv = load_fast(fpoll + off);
        if (__all((int)((unsigned int)(fv >> 32) >= (unsigned int)t))) { v = fv; break; }
        if (((++spin) & 3) == 0) {
          u64 sv = __hip_atomic_load(spoll + off, __ATOMIC_RELAXED,
                                     __HIP_MEMORY_SCOPE_AGENT);
          u64 cvv = ((unsigned int)(fv >> 32) >= (unsigned int)t) ? fv : sv;
          if (__all((int)((unsigned int)(cvv >> 32) >= (unsigned int)t))) { v = cvv; break; }
        }
      }
      hval = __uint_as_float((unsigned int)v);
      // lagged out-write off the critical path (one writer per column: w==g)
      if (diag)
        out[bo + (size_t)(t - 1) * HH + j] = hval;
    }
    if (t < TT) {
      f32x2 au2 = {0.f, 0.f}, ar2 = {0.f, 0.f}, ac2 = {0.f, 0.f};
      const unsigned int hbits = __float_as_uint(hval);
      #pragma unroll
      for (int i = 0; i < 32; ++i) {
        f32x2 hp;
        hp.x = __uint_as_float(__builtin_amdgcn_readlane(hbits, 2 * i));
        hp.y = __uint_as_float(__builtin_amdgcn_readlane(hbits, 2 * i + 1));
        au2 = __builtin_elementwise_fma(hp, wu2[i], au2);
        ar2 = __builtin_elementwise_fma(hp, wr2[i], ar2);
        ac2 = __builtin_elementwise_fma(hp, wc2[i], ac2);
      }
      const int pb = t & 1;
      parts[pb][w][0][l] = au2.x + au2.y;
      parts[pb][w][1][l] = ar2.x + ar2.y;
      parts[pb][w][2][l] = ac2.x + ac2.y;
      wg_barrier_lgkm();
      if (w == 0) {
        float su = 0.f, sr = 0.f, sc = 0.f;
        #pragma unroll
        for (int ww = 0; ww < 8; ++ww) {
          su += parts[pb][ww][0][l];
          sr += parts[pb][ww][1][l];
          sc += parts[pb][ww][2][l];
        }
        const float ux = __half2float(__ushort_as_half((unsigned short)(urx_c & 0xffffu)));
        const float rx = __half2float(__ushort_as_half((unsigned short)(urx_c >> 16)));
        const float cxf = __half2float(__ushort_as_half(cx_c));
        const float uu = fast_sigmoid(su + ux);
        const float rr = fast_sigmoid(sr + rx);
        const float ccv = fast_tanh(cxf + rr * sc);
        const float h = hprev + uu * (ccv - hprev);
        hprev = h;
        // publish FIRST: fast (XCD-L2) then slow (LLC); both tagged 8B words
        const u64 pv = ((u64)(unsigned int)(t + 1) << 32) | (u64)__float_as_uint(h);
        const size_t poff = (size_t)((t + 1) & 1) * (BB * HH);
        store_fast(fpub + poff, pv);
        __hip_atomic_store(spub + poff, pv, __ATOMIC_RELAXED,
                           __HIP_MEMORY_SCOPE_AGENT);
        // non-critical: next-step proj prefetch (lands during next poll)
        if (t + 1 < TT) {
          urx_c = outu[bo + (size_t)(t + 1) * HH + j];
          cx_c  = cxu[bo + (size_t)(t + 1) * HH + j];
        }
      }
      // no second barrier: double-buffered parts removes the WAR hazard
    }
  }
}

// ---------------------------------------------------------------------------
extern "C" void kernel_launch(void* const* d_in, const int* in_sizes, int n_in,
                              void* d_out, int out_size, void* d_ws, size_t ws_size,
                              hipStream_t stream) {
  const float* x    = (const float*)d_in[0];
  const float* wu_i = (const float*)d_in[1];
  const float* wu_h = (const float*)d_in[2];
  const float* bu   = (const float*)d_in[3];
  const float* wr_i = (const float*)d_in[4];
  const float* wr_h = (const float*)d_in[5];
  const float* br   = (const float*)d_in[6];
  const float* wc_i = (const float*)d_in[7];
  const float* wc_h = (const float*)d_in[8];
  const float* bc   = (const float*)d_in[9];
  float* out = (float*)d_out;

  // ws layout (~67.2 MiB total)
  char* ws = (char*)d_ws;
  __half* cx = (__half*)ws;                                  // 64 MiB c_x f16
  unsigned short* wuT  = (unsigned short*)(ws + (size_t)MM * HH * 2);
  unsigned short* wrT  = wuT + HH * HH;
  unsigned short* wcTh = wrT + HH * HH;
  unsigned short* wcTl = wcTh + HH * HH;
  u64* hfast = (u64*)(wcTl + HH * HH);                       // [2][BB][HH] u64
  u64* hslow = hfast + 2 * BB * HH;                          // [2][BB][HH] u64

  hipMemsetAsync(hfast, 0, (size_t)4 * BB * HH * sizeof(u64), stream);
  wconv_kernel<<<1024, 256, 0, stream>>>(wu_i, wr_i, wc_i, wuT, wrT, wcTh, wcTl);
  proj_gemm<0><<<dim3(MM / 128, 8), 256, 0, stream>>>(x, wuT, wrT, bu, br, (void*)out);
  proj_gemm<1><<<dim3(MM / 128, 8), 256, 0, stream>>>(x, wcTh, wcTl, bc, bc, (void*)cx);

  void* args[] = { (void*)&wu_h, (void*)&wr_h, (void*)&wc_h, (void*)&out,
                   (void*)&cx, (void*)&hfast, (void*)&hslow };
  hipLaunchCooperativeKernel((void*)scan_kernel, dim3(256), dim3(512), args, 0, stream);
}